// Round 6
// baseline (240.834 us; speedup 1.0000x reference)
//
#include <hip/hip_runtime.h>
#include <hip/hip_fp16.h>

#define NMESH 128
#define NMESH2 (128 * 128)
#define NMESH3 (128 * 128 * 128)
#define NPOINTS 100000
#define NCH 16

#define NBINS_DIM 16     // 16^3 bins
#define NBINS 4096
#define BINW 8           // cells per bin per dim
#define HALO 10          // staged cells per dim (8 + 1 halo each side)
#define BIN_CAP 64       // max points per bin (Poisson mean 24.4; P(>64) ~ 1e-15)

// ---------------------------------------------------------------------------
// Kernel 1 (v4, unchanged): transpose (C,X,Y,Z) fp32 -> (X,Y,Z,C) fp16.
// ---------------------------------------------------------------------------
__global__ __launch_bounds__(256) void transpose_to_half_v4(
    const float* __restrict__ in,   // [16][2M]
    __half* __restrict__ outT)      // [2M][16]
{
    __shared__ float lds[2][NCH * 256];   // 2 x 16 KB
    const int t = threadIdx.x;
    const int f = t & 63;
    const int c0 = t >> 6;
    const int nTiles = NMESH3 / 256;      // 8192

    int buf = 0;
    for (int tile = blockIdx.x; tile < nTiles; tile += gridDim.x, buf ^= 1) {
        const int s_base = tile * 256;
#pragma unroll
        for (int k = 0; k < 4; ++k) {
            const int c = (c0 + 4 * k + tile) & 15;
            const float4 v =
                *(const float4*)(in + (size_t)c * NMESH3 + s_base + 4 * f);
            *(float4*)&lds[buf][c * 256 + 4 * f] = v;
        }
        __syncthreads();
        uint4* o = (uint4*)(outT + (size_t)s_base * NCH);
#pragma unroll
        for (int r = 0; r < 2; ++r) {
            const int i = t + 256 * r;
            const int s = i >> 1;
            const int h = (i & 1) * 8;
            uint32_t w[4];
#pragma unroll
            for (int m = 0; m < 4; ++m) {
                const float f0 = lds[buf][(h + 2 * m + 0) * 256 + s];
                const float f1 = lds[buf][(h + 2 * m + 1) * 256 + s];
                w[m] = (uint32_t)__half_as_ushort(__float2half(f0)) |
                       ((uint32_t)__half_as_ushort(__float2half(f1)) << 16);
            }
            o[i] = make_uint4(w[0], w[1], w[2], w[3]);
        }
    }
}

// ---------------------------------------------------------------------------
// Binning pass A: zero the per-bin counters.
// ---------------------------------------------------------------------------
__global__ __launch_bounds__(256) void bin_zero_kernel(int* __restrict__ bin_count)
{
    const int i = blockIdx.x * 256 + threadIdx.x;
    if (i < NBINS) bin_count[i] = 0;
}

// ---------------------------------------------------------------------------
// Binning pass B: scatter point indices into spatial bins (8^3 cells/bin).
// rx/ry/rz computed with EXACTLY the same expressions as the gather so the
// bin assignment and the gather's cell coords agree bit-for-bit.
// ---------------------------------------------------------------------------
__global__ __launch_bounds__(256) void bin_scatter_kernel(
    const float* __restrict__ pts,
    int* __restrict__ bin_count,
    int* __restrict__ sorted_p)
{
    const int p = blockIdx.x * 256 + threadIdx.x;
    if (p >= NPOINTS) return;

    const float SP = 0.1f;
    const float pcx = pts[p * 3 + 0] / SP;
    const float pcy = pts[p * 3 + 1] / SP;
    const float pcz = pts[p * 3 + 2] / SP;
    const int rxw = (int)rintf(pcx) & (NMESH - 1);
    const int ryw = (int)rintf(pcy) & (NMESH - 1);
    const int rzw = (int)rintf(pcz) & (NMESH - 1);

    const int b = ((rxw >> 3) << 8) | ((ryw >> 3) << 4) | (rzw >> 3);
    const int slot = atomicAdd(&bin_count[b], 1);
    if (slot < BIN_CAP) sorted_p[b * BIN_CAP + slot] = p;
}

// ---------------------------------------------------------------------------
// Kernel 2 (REWRITTEN): binned gather. One block per bin (4096 blocks).
//   - stage the bin's 10x10x10-cell halo region (32000 B fp16) into LDS
//     (coalesced: cells are 32 B; z-runs of 10 cells = 320 B contiguous)
//   - each point: 4 lanes (channel quads), 27 taps -> LDS reads instead of
//     random L3 traffic. Weight math & tap order identical to the previous
//     gather => bitwise-identical output per point.
// ---------------------------------------------------------------------------
__global__ __launch_bounds__(256) void binned_gather_kernel(
    const __half* __restrict__ meshT,   // [2M][16]
    const float* __restrict__ pts,      // [100000][3]
    const int* __restrict__ bin_count,
    const int* __restrict__ sorted_p,
    float4* __restrict__ out)           // [100000][4] of float4
{
    __shared__ __half tile[HALO * HALO * HALO * NCH];   // 32000 B

    const int b = blockIdx.x;
    const int bx = b >> 8;
    const int by = (b >> 4) & 15;
    const int bz = b & 15;
    const int gx0 = bx * BINW - 1;
    const int gy0 = by * BINW - 1;
    const int gz0 = bz * BINW - 1;

    // Stage 1000 cells, 2 x uint4 each.
    for (int ci = threadIdx.x; ci < HALO * HALO * HALO; ci += 256) {
        const int lx = ci / 100;
        const int rem = ci - lx * 100;
        const int ly = rem / 10;
        const int lz = rem - ly * 10;
        const int gx = (gx0 + lx) & (NMESH - 1);
        const int gy = (gy0 + ly) & (NMESH - 1);
        const int gz = (gz0 + lz) & (NMESH - 1);
        const uint4* src =
            (const uint4*)(meshT + ((size_t)(gx * NMESH + gy) * NMESH + gz) * NCH);
        uint4* dst = (uint4*)(tile + ci * NCH);
        dst[0] = src[0];
        dst[1] = src[1];
    }
    __syncthreads();

    const int cnt = min(bin_count[b], BIN_CAP);
    const int q = threadIdx.x & 3;   // channel quad

    for (int g = threadIdx.x >> 2; g < cnt; g += 64) {
        const int p = sorted_p[b * BIN_CAP + g];

        const float SP = 0.1f;
        const float pcx = pts[p * 3 + 0] / SP;
        const float pcy = pts[p * 3 + 1] / SP;
        const float pcz = pts[p * 3 + 2] / SP;

        const int rx = (int)rintf(pcx);
        const int ry = (int)rintf(pcy);
        const int rz = (int)rintf(pcz);

        const float dx = pcx - (float)rx;
        const float dy = pcy - (float)ry;
        const float dz = pcz - (float)rz;

        float wX[3], wY[3], wZ[3];
        wX[0] = (2.0f * dx - 1.0f) * (2.0f * dx - 1.0f) * 0.125f;
        wX[1] = 0.75f - dx * dx;
        wX[2] = (2.0f * dx + 1.0f) * (2.0f * dx + 1.0f) * 0.125f;
        wY[0] = (2.0f * dy - 1.0f) * (2.0f * dy - 1.0f) * 0.125f;
        wY[1] = 0.75f - dy * dy;
        wY[2] = (2.0f * dy + 1.0f) * (2.0f * dy + 1.0f) * 0.125f;
        wZ[0] = (2.0f * dz - 1.0f) * (2.0f * dz - 1.0f) * 0.125f;
        wZ[1] = 0.75f - dz * dz;
        wZ[2] = (2.0f * dz + 1.0f) * (2.0f * dz + 1.0f) * 0.125f;

        // local (staged) coords: cell of this point is within the bin
        const int lrx = (rx & (NMESH - 1)) - bx * BINW + 1;   // 1..8
        const int lry = (ry & (NMESH - 1)) - by * BINW + 1;
        const int lrz = (rz & (NMESH - 1)) - bz * BINW + 1;

        float4 acc = make_float4(0.0f, 0.0f, 0.0f, 0.0f);
#pragma unroll
        for (int a = 0; a < 3; ++a) {
#pragma unroll
            for (int bb = 0; bb < 3; ++bb) {
                const int lx = lrx - 1 + a;
                const int ly = lry - 1 + bb;
                const __half* base =
                    tile + ((lx * HALO + ly) * HALO + (lrz - 1)) * NCH + q * 4;
                const float wxy = wX[a] * wY[bb];
#pragma unroll
                for (int k = 0; k < 3; ++k) {
                    union { uint2 u; __half2 h[2]; } d;
                    d.u = *(const uint2*)(base + k * NCH);
                    const float2 f01 = __half22float2(d.h[0]);
                    const float2 f23 = __half22float2(d.h[1]);
                    const float w = wxy * wZ[k];
                    acc.x = fmaf(f01.x, w, acc.x);
                    acc.y = fmaf(f01.y, w, acc.y);
                    acc.z = fmaf(f23.x, w, acc.z);
                    acc.w = fmaf(f23.y, w, acc.w);
                }
            }
        }
        out[p * 4 + q] = acc;
    }
}

// ---------------------------------------------------------------------------
// Fallback in case ws_size is too small.
// ---------------------------------------------------------------------------
__global__ __launch_bounds__(256) void mesh_interp_fallback_kernel(
    const float* __restrict__ mesh,
    const float* __restrict__ pts,
    float* __restrict__ out)
{
    const int tid = blockIdx.x * 256 + threadIdx.x;
    const int c = tid & (NCH - 1);
    const int p = tid >> 4;
    if (p >= NPOINTS) return;

    const float SP = 0.1f;
    const float pcx = pts[p * 3 + 0] / SP;
    const float pcy = pts[p * 3 + 1] / SP;
    const float pcz = pts[p * 3 + 2] / SP;

    const int rx = (int)rintf(pcx);
    const int ry = (int)rintf(pcy);
    const int rz = (int)rintf(pcz);

    const float dx = pcx - (float)rx;
    const float dy = pcy - (float)ry;
    const float dz = pcz - (float)rz;

    float wX[3], wY[3], wZ[3];
    wX[0] = (2.0f * dx - 1.0f) * (2.0f * dx - 1.0f) * 0.125f;
    wX[1] = 0.75f - dx * dx;
    wX[2] = (2.0f * dx + 1.0f) * (2.0f * dx + 1.0f) * 0.125f;
    wY[0] = (2.0f * dy - 1.0f) * (2.0f * dy - 1.0f) * 0.125f;
    wY[1] = 0.75f - dy * dy;
    wY[2] = (2.0f * dy + 1.0f) * (2.0f * dy + 1.0f) * 0.125f;
    wZ[0] = (2.0f * dz - 1.0f) * (2.0f * dz - 1.0f) * 0.125f;
    wZ[1] = 0.75f - dz * dz;
    wZ[2] = (2.0f * dz + 1.0f) * (2.0f * dz + 1.0f) * 0.125f;

    int xb[3], yb[3], zi[3];
#pragma unroll
    for (int k = 0; k < 3; ++k) {
        xb[k] = ((rx - 1 + k) & (NMESH - 1)) * NMESH2;
        yb[k] = ((ry - 1 + k) & (NMESH - 1)) * NMESH;
        zi[k] = ((rz - 1 + k) & (NMESH - 1));
    }

    const float* __restrict__ mc = mesh + (size_t)c * NMESH3;
    float acc = 0.0f;
#pragma unroll
    for (int a = 0; a < 3; ++a) {
#pragma unroll
        for (int b = 0; b < 3; ++b) {
            const float* __restrict__ row = mc + xb[a] + yb[b];
            const float wxy = wX[a] * wY[b];
            acc = fmaf(row[zi[0]], wxy * wZ[0], acc);
            acc = fmaf(row[zi[1]], wxy * wZ[1], acc);
            acc = fmaf(row[zi[2]], wxy * wZ[2], acc);
        }
    }
    out[tid] = acc;
}

extern "C" void kernel_launch(void* const* d_in, const int* in_sizes, int n_in,
                              void* d_out, int out_size, void* d_ws, size_t ws_size,
                              hipStream_t stream) {
    const float* mesh = (const float*)d_in[0];
    const float* pts  = (const float*)d_in[1];

    const size_t meshT_bytes = (size_t)NMESH3 * NCH * sizeof(__half);  // 64 MiB
    const size_t count_bytes = (size_t)NBINS * sizeof(int);            // 16 KiB
    const size_t sorted_bytes = (size_t)NBINS * BIN_CAP * sizeof(int); // 1 MiB
    const size_t needed = meshT_bytes + count_bytes + sorted_bytes;

    if (ws_size >= needed) {
        __half* meshT = (__half*)d_ws;
        int* bin_count = (int*)((char*)d_ws + meshT_bytes);
        int* sorted_p = bin_count + NBINS;

        transpose_to_half_v4<<<2048, 256, 0, stream>>>(mesh, meshT);
        bin_zero_kernel<<<NBINS / 256, 256, 0, stream>>>(bin_count);
        bin_scatter_kernel<<<(NPOINTS + 255) / 256, 256, 0, stream>>>(
            pts, bin_count, sorted_p);
        binned_gather_kernel<<<NBINS, 256, 0, stream>>>(
            meshT, pts, bin_count, sorted_p, (float4*)d_out);
    } else {
        const int total = NPOINTS * NCH;
        mesh_interp_fallback_kernel<<<(total + 255) / 256, 256, 0, stream>>>(
            mesh, pts, (float*)d_out);
    }
}